// Round 4
// baseline (149.958 us; speedup 1.0000x reference)
//
#include <hip/hip_runtime.h>
#include <hip/hip_bf16.h>

#define B_ROWS 8192
#define C_IN   4096
#define G_GRP  8
#define CG     512
#define J_RANK 512
#define BK     32
#define NKB    (CG / BK)   // 16 K-steps

typedef __attribute__((ext_vector_type(8))) short bf16x8;
typedef __attribute__((ext_vector_type(4))) float f32x4;
typedef __attribute__((ext_vector_type(8))) unsigned short u16x8;

struct ushort4v { unsigned short x, y, z, w; };

__device__ __forceinline__ unsigned short f2bf(float f) {
    unsigned int u = __float_as_uint(f);
    unsigned int r = (u + 0x7FFFu + ((u >> 16) & 1u)) >> 16;  // RNE
    return (unsigned short)r;
}

// ---------------- kernel 1: convert weights fp32 -> bf16 ----------------
__global__ __launch_bounds__(256) void convert_w_kernel(
    const float* __restrict__ w, unsigned short* __restrict__ wb, int n4) {
    int i = blockIdx.x * 256 + threadIdx.x;
    if (i >= n4) return;
    float4 v = ((const float4*)w)[i];
    ushort4v o;
    o.x = f2bf(v.x); o.y = f2bf(v.y); o.z = f2bf(v.z); o.w = f2bf(v.w);
    ((ushort4v*)wb)[i] = o;
}

// -------- kernel 2: gather-permute x, barrier-free scattered gather -----
// One block per FULL row (8192 blocks): the whole 16KB row is consumed by
// this block -> its ~256 cache lines are fetched exactly once into this
// XCD's L1/L2 (no cross-XCD duplication, unlike quarter-row blocks).
// arr indices hoisted (16 independent loads, L2-hot), then 16 independent
// scattered 4B gathers per thread (deep MLP, no barriers, no LDS), then
// 2 coalesced 16B bf16 stores.
__global__ __launch_bounds__(256) void permute_x_kernel(
    const float* __restrict__ x, const int* __restrict__ arr,
    unsigned short* __restrict__ xp) {
    const int b   = blockIdx.x;
    const int tid = threadIdx.x;

    // arrangements declared int64 in the reference; harness may hand int32.
    // int64 little-endian => odd int32 words all 0 (values < 4096).
    const bool is64 = (arr[1] == 0 && arr[3] == 0 && arr[5] == 0 && arr[7] == 0);

    const float* xrow = x + (size_t)b * C_IN;
    unsigned short* orow = xp + (size_t)b * C_IN;

    int sidx[16];
#pragma unroll
    for (int pass = 0; pass < 2; ++pass)
#pragma unroll
        for (int k = 0; k < 8; ++k) {
            int p = pass * 2048 + tid * 8 + k;
            sidx[pass * 8 + k] = is64 ? arr[2 * p] : arr[p];
        }

    float v[16];
#pragma unroll
    for (int i = 0; i < 16; ++i) v[i] = xrow[sidx[i]];   // independent gathers

#pragma unroll
    for (int pass = 0; pass < 2; ++pass) {
        u16x8 o;
#pragma unroll
        for (int k = 0; k < 8; ++k) o[k] = f2bf(v[pass * 8 + k]);
        *(u16x8*)(orow + pass * 2048 + tid * 8) = o;
    }
}

// ---------------- kernel 3: grouped GEMM (bf16 MFMA) ---------------------
// 128x256 tile, BK=32, double-buffered LDS, 2-phase prefetch with COUNTED
// vmcnt (T4): the barrier waits only for the CURRENT buffer's 6 loads
// (issued one full K-step earlier); the next tile's 6 stay in flight.
__global__ __launch_bounds__(256) void gemm_kernel(
    const unsigned short* __restrict__ Xp,   // [B][4096] bf16 (permuted)
    const unsigned short* __restrict__ Wb,   // [G][J][CG] bf16
    const float* __restrict__ bias,          // [G][J]
    float* __restrict__ out) {               // [B][4096] fp32
    __shared__ unsigned short ldsA[2][128 * BK];   // 2 x 8KB
    __shared__ unsigned short ldsB[2][256 * BK];   // 2 x 16KB

    const int tid = threadIdx.x;
    // bijective XCD swizzle: 1024 blocks, 8 XCDs, 128 each -> group g pinned
    // to XCD g; its 512KB B-panel stays L2-resident.
    const int lid = (blockIdx.x & 7) * 128 + (blockIdx.x >> 3);
    const int g   = lid >> 7;          // 8 groups x 128 blocks
    const int mt  = (lid & 127) >> 1;  // 64 m-tiles
    const int nt  = lid & 1;           // 2 n-tiles (256 cols each)

    const int l  = tid & 63;
    const int wv = tid >> 6;           // wave 0..3
    const int wr = wv >> 1;            // wave row 0..1 (64 rows each)
    const int wc = wv & 1;             // wave col 0..1 (128 cols each)
    const int lr = l & 15;
    const int lk = (l >> 4) << 3;      // k-slice 0,8,16,24

    const unsigned short* Abase = Xp + (size_t)(mt * 128) * C_IN + g * CG;
    const unsigned short* Bbase = Wb + (size_t)g * J_RANK * CG + (size_t)(nt * 256) * CG;

    f32x4 acc[4][8];
#pragma unroll
    for (int m = 0; m < 4; ++m)
#pragma unroll
        for (int n = 0; n < 8; ++n) acc[m][n] = (f32x4){0.f, 0.f, 0.f, 0.f};

#define STAGE(bufi, kb)                                                          \
    do {                                                                         \
        _Pragma("unroll")                                                        \
        for (int i = 0; i < 2; ++i) {                                            \
            int c = i * 256 + tid;                                               \
            int row = c >> 2, cc = c & 3;                                        \
            __builtin_amdgcn_global_load_lds(                                    \
                (const __attribute__((address_space(1))) unsigned int*)          \
                    (Abase + (size_t)row * C_IN + (kb) * BK + cc * 8),           \
                (__attribute__((address_space(3))) unsigned int*)                \
                    (&ldsA[bufi][0] + c * 8),                                    \
                16, 0, 0);                                                       \
        }                                                                        \
        _Pragma("unroll")                                                        \
        for (int i = 0; i < 4; ++i) {                                            \
            int c = i * 256 + tid;                                               \
            int row = c >> 2, cc = c & 3;                                        \
            __builtin_amdgcn_global_load_lds(                                    \
                (const __attribute__((address_space(1))) unsigned int*)          \
                    (Bbase + (size_t)row * CG + (kb) * BK + cc * 8),             \
                (__attribute__((address_space(3))) unsigned int*)                \
                    (&ldsB[bufi][0] + c * 8),                                    \
                16, 0, 0);                                                       \
        }                                                                        \
    } while (0)

    STAGE(0, 0);

    int buf = 0;
    for (int kb = 0; kb < NKB; ++kb) {
        if (kb + 1 < NKB) {
            STAGE(buf ^ 1, kb + 1);                            // 6 loads in flight
            asm volatile("s_waitcnt vmcnt(6)" ::: "memory");   // current buf ready
        } else {
            asm volatile("s_waitcnt vmcnt(0)" ::: "memory");
        }
        __builtin_amdgcn_s_barrier();        // all waves: buf staged
        __builtin_amdgcn_sched_barrier(0);

        bf16x8 af[4], bfr[8];
#pragma unroll
        for (int m = 0; m < 4; ++m)
            af[m] = *(const bf16x8*)&ldsA[buf][(wr * 64 + m * 16 + lr) * BK + lk];
#pragma unroll
        for (int n = 0; n < 8; ++n)
            bfr[n] = *(const bf16x8*)&ldsB[buf][(wc * 128 + n * 16 + lr) * BK + lk];
#pragma unroll
        for (int m = 0; m < 4; ++m)
#pragma unroll
            for (int n = 0; n < 8; ++n)
                acc[m][n] = __builtin_amdgcn_mfma_f32_16x16x32_bf16(
                    af[m], bfr[n], acc[m][n], 0, 0, 0);

        __builtin_amdgcn_sched_barrier(0);
        __builtin_amdgcn_s_barrier();        // all reads of buf done before overwrite
        buf ^= 1;
    }
#undef STAGE

    // epilogue: D frag layout col = lane&15, row = (lane>>4)*4 + r
    const int r0 = mt * 128 + wr * 64 + ((l >> 4) << 2);
    const int cbase = nt * 256 + wc * 128 + lr;   // within group's 512 cols
#pragma unroll
    for (int n = 0; n < 8; ++n) {
        int col = cbase + n * 16;
        float bv = bias[g * J_RANK + col];
#pragma unroll
        for (int m = 0; m < 4; ++m) {
            int row = r0 + m * 16;
            float* op = out + (size_t)row * C_IN + g * J_RANK + col;
#pragma unroll
            for (int r = 0; r < 4; ++r)
                op[(size_t)r * C_IN] = acc[m][n][r] + bv;
        }
    }
}

extern "C" void kernel_launch(void* const* d_in, const int* in_sizes, int n_in,
                              void* d_out, int out_size, void* d_ws, size_t ws_size,
                              hipStream_t stream) {
    const float* x    = (const float*)d_in[0];
    const int*   arr  = (const int*)d_in[1];
    const float* w    = (const float*)d_in[2];
    const float* bias = (const float*)d_in[3];
    float* out = (float*)d_out;

    // workspace: xp bf16 [8192][4096] (64MB) | wb bf16 [8][512][512] (4MB)
    unsigned short* xp = (unsigned short*)d_ws;
    unsigned short* wb = xp + (size_t)B_ROWS * C_IN;

    hipLaunchKernelGGL(convert_w_kernel, dim3((G_GRP * J_RANK * CG / 4 + 255) / 256),
                       dim3(256), 0, stream, w, wb, G_GRP * J_RANK * CG / 4);
    hipLaunchKernelGGL(permute_x_kernel, dim3(B_ROWS), dim3(256), 0, stream,
                       x, arr, xp);
    hipLaunchKernelGGL(gemm_kernel, dim3(G_GRP * 128), dim3(256), 0, stream,
                       xp, wb, bias, out);
}

// Round 5
// 116.863 us; speedup vs baseline: 1.2832x; 1.2832x over previous
//
#include <hip/hip_runtime.h>
#include <hip/hip_bf16.h>

#define B_ROWS 8192
#define C_IN   4096
#define G_GRP  8
#define CG     512
#define J_RANK 512
#define GBK    32
#define GNKB   (CG / GBK)   // 16 K-steps

#define RPB    16                     // rows per permute block
#define PERM_BLOCKS (B_ROWS / RPB)    // 512

typedef __attribute__((ext_vector_type(8))) short bf16x8;
typedef __attribute__((ext_vector_type(4))) float f32x4;
typedef __attribute__((ext_vector_type(8))) unsigned short u16x8;

struct ushort4v { unsigned short x, y, z, w; };

__device__ __forceinline__ unsigned short f2bf(float f) {
    unsigned int u = __float_as_uint(f);
    unsigned int r = (u + 0x7FFFu + ((u >> 16) & 1u)) >> 16;  // RNE
    return (unsigned short)r;
}

// ---------------- kernel 1: convert weights fp32 -> bf16 ----------------
__global__ __launch_bounds__(256) void convert_w_kernel(
    const float* __restrict__ w, unsigned short* __restrict__ wb, int n4) {
    int i = blockIdx.x * 256 + threadIdx.x;
    if (i >= n4) return;
    float4 v = ((const float4*)w)[i];
    ushort4v o;
    o.x = f2bf(v.x); o.y = f2bf(v.y); o.z = f2bf(v.z); o.w = f2bf(v.w);
    ((ushort4v*)wb)[i] = o;
}

// -------- kernel 2: gather-permute x, depth-3 LDS pipeline --------------
// 512 blocks x 16 rows (exactly 2 blocks/CU co-resident at 48KB LDS).
// Gather goes through LDS (global scatter is TA-throughput-bound, R4 evidence).
// arr indices hoisted once. Counted vmcnt: stage loads (4/thread/row) issued
// 3 rows ahead; steady-state wait vmcnt(12) = keep {S_{r-2},L_{r+1},S_{r-1},
// L_{r+2}} in flight. Issue order per wave:
//   L0 L1 L2 | [w0 S0 L3] [w1 S1 L4] ... [w_r S_r L_{r+3}] ...
// ladder: r0:8  r1:10  r2..13:12  r14:8  r15:4
__global__ __launch_bounds__(256) void permute_x_kernel(
    const float* __restrict__ x, const int* __restrict__ arr,
    unsigned short* __restrict__ xp) {
    __shared__ float buf[3][C_IN];   // 48 KB
    const int tid  = threadIdx.x;
    const int row0 = blockIdx.x * RPB;

    // arrangements declared int64 in the reference; harness may hand int32.
    // int64 little-endian => odd int32 words all 0 (values < 4096).
    const bool is64 = (arr[1] == 0 && arr[3] == 0 && arr[5] == 0 && arr[7] == 0);

    int sidx[16];
#pragma unroll
    for (int pass = 0; pass < 2; ++pass)
#pragma unroll
        for (int k = 0; k < 8; ++k) {
            int p = pass * 2048 + tid * 8 + k;
            sidx[pass * 8 + k] = is64 ? arr[2 * p] : arr[p];
        }

#define PSTAGE(bufi, r)                                                      \
    do {                                                                     \
        const float* src_ = x + (size_t)(row0 + (r)) * C_IN;                 \
        _Pragma("unroll")                                                    \
        for (int i_ = 0; i_ < 4; ++i_) {                                     \
            int c_ = i_ * 256 + tid;                                         \
            __builtin_amdgcn_global_load_lds(                                \
                (const __attribute__((address_space(1))) unsigned int*)      \
                    (src_ + c_ * 4),                                         \
                (__attribute__((address_space(3))) unsigned int*)            \
                    (&buf[bufi][0] + c_ * 4),                                \
                16, 0, 0);                                                   \
        }                                                                    \
    } while (0)

    PSTAGE(0, 0);
    PSTAGE(1, 1);
    PSTAGE(2, 2);

#pragma unroll
    for (int r = 0; r < RPB; ++r) {
        if (r == 0)            asm volatile("s_waitcnt vmcnt(8)"  ::: "memory");
        else if (r == 1)       asm volatile("s_waitcnt vmcnt(10)" ::: "memory");
        else if (r == RPB - 2) asm volatile("s_waitcnt vmcnt(8)"  ::: "memory");
        else if (r == RPB - 1) asm volatile("s_waitcnt vmcnt(4)"  ::: "memory");
        else                   asm volatile("s_waitcnt vmcnt(12)" ::: "memory");
        __builtin_amdgcn_s_barrier();          // whole block's row r in LDS
        __builtin_amdgcn_sched_barrier(0);

        const int bi = r % 3;                  // compile-time (unrolled)
        unsigned short* orow = xp + (size_t)(row0 + r) * C_IN;
#pragma unroll
        for (int pass = 0; pass < 2; ++pass) {
            u16x8 o;
#pragma unroll
            for (int k = 0; k < 8; ++k)
                o[k] = f2bf(buf[bi][sidx[pass * 8 + k]]);
            *(u16x8*)(orow + pass * 2048 + tid * 8) = o;
        }

        __builtin_amdgcn_sched_barrier(0);
        __builtin_amdgcn_s_barrier();          // all waves done reading buf[bi]
        if (r + 3 < RPB) PSTAGE(bi, r + 3);    // slot (r+3)%3 == bi, now safe
    }
#undef PSTAGE
}

// ---------------- kernel 3: grouped GEMM (bf16 MFMA) ---------------------
// 128x512 tile, 8 waves (2x4), BK=32, double-buffered LDS (80KB -> exactly
// 2 blocks/CU, 512-block grid fully co-resident). A (xp) read ONCE.
// g = blockIdx&7 pins each group to one XCD: its 0.5MB B-panel L2-resident.
// Counted vmcnt(5): stage next tile at loop top; wait only for current.
__global__ __launch_bounds__(512, 2) void gemm_kernel(
    const unsigned short* __restrict__ Xp,   // [B][4096] bf16 (permuted)
    const unsigned short* __restrict__ Wb,   // [G][J][CG] bf16
    const float* __restrict__ bias,          // [G][J]
    float* __restrict__ out) {               // [B][4096] fp32
    __shared__ unsigned short ldsA[2][128 * GBK];   // 2 x 8 KB
    __shared__ unsigned short ldsB[2][512 * GBK];   // 2 x 32 KB

    const int tid = threadIdx.x;
    const int g   = blockIdx.x & 7;    // group -> XCD (round-robin dispatch)
    const int mt  = blockIdx.x >> 3;   // 64 m-tiles

    const int l  = tid & 63;
    const int wv = tid >> 6;           // wave 0..7
    const int wr = wv >> 2;            // wave row 0..1 (64 rows each)
    const int wc = wv & 3;             // wave col 0..3 (128 cols each)
    const int lr = l & 15;
    const int lk = (l >> 4) << 3;      // k-slice 0,8,16,24

    const unsigned short* Abase = Xp + (size_t)(mt * 128) * C_IN + g * CG;
    const unsigned short* Bbase = Wb + (size_t)g * J_RANK * CG;

    f32x4 acc[4][8];
#pragma unroll
    for (int m = 0; m < 4; ++m)
#pragma unroll
        for (int n = 0; n < 8; ++n) acc[m][n] = (f32x4){0.f, 0.f, 0.f, 0.f};

#define GSTAGE(slot, kb)                                                         \
    do {                                                                         \
        /* A: 128x32 = 512 x 16B chunks, 1/thread */                             \
        {                                                                        \
            int c = tid;                                                         \
            __builtin_amdgcn_global_load_lds(                                    \
                (const __attribute__((address_space(1))) unsigned int*)          \
                    (Abase + (size_t)(c >> 2) * C_IN + (kb) * GBK + (c & 3) * 8),\
                (__attribute__((address_space(3))) unsigned int*)                \
                    (&ldsA[slot][0] + c * 8),                                    \
                16, 0, 0);                                                       \
        }                                                                        \
        /* B: 512x32 = 2048 x 16B chunks, 4/thread */                            \
        _Pragma("unroll")                                                        \
        for (int i = 0; i < 4; ++i) {                                            \
            int cb = i * 512 + tid;                                              \
            __builtin_amdgcn_global_load_lds(                                    \
                (const __attribute__((address_space(1))) unsigned int*)          \
                    (Bbase + (size_t)(cb >> 2) * CG + (kb) * GBK + (cb & 3) * 8),\
                (__attribute__((address_space(3))) unsigned int*)                \
                    (&ldsB[slot][0] + cb * 8),                                   \
                16, 0, 0);                                                       \
        }                                                                        \
    } while (0)

    GSTAGE(0, 0);

    for (int kb = 0; kb < GNKB; ++kb) {
        const int sl = kb & 1;
        if (kb + 1 < GNKB) {
            GSTAGE(sl ^ 1, kb + 1);   // writes slot read in iter kb-1 (done)
            asm volatile("s_waitcnt vmcnt(5)" ::: "memory");  // current ready
        } else {
            asm volatile("s_waitcnt vmcnt(0)" ::: "memory");
        }
        __builtin_amdgcn_s_barrier();
        __builtin_amdgcn_sched_barrier(0);

        bf16x8 af[4], bfr[8];
#pragma unroll
        for (int m = 0; m < 4; ++m)
            af[m] = *(const bf16x8*)&ldsA[sl][(wr * 64 + m * 16 + lr) * GBK + lk];
#pragma unroll
        for (int n = 0; n < 8; ++n)
            bfr[n] = *(const bf16x8*)&ldsB[sl][(wc * 128 + n * 16 + lr) * GBK + lk];
#pragma unroll
        for (int m = 0; m < 4; ++m)
#pragma unroll
            for (int n = 0; n < 8; ++n)
                acc[m][n] = __builtin_amdgcn_mfma_f32_16x16x32_bf16(
                    af[m], bfr[n], acc[m][n], 0, 0, 0);

        __builtin_amdgcn_sched_barrier(0);
        __builtin_amdgcn_s_barrier();   // all reads of slot sl done
    }
#undef GSTAGE

    // epilogue: D frag layout col = lane&15, row = (lane>>4)*4 + r
    const int r0 = mt * 128 + wr * 64 + ((l >> 4) << 2);
    const int cbase = wc * 128 + lr;   // within group's 512 cols
#pragma unroll
    for (int n = 0; n < 8; ++n) {
        int col = cbase + n * 16;
        float bv = bias[g * J_RANK + col];
#pragma unroll
        for (int m = 0; m < 4; ++m) {
            int row = r0 + m * 16;
            float* op = out + (size_t)row * C_IN + g * J_RANK + col;
#pragma unroll
            for (int r = 0; r < 4; ++r)
                op[(size_t)r * C_IN] = acc[m][n][r] + bv;
        }
    }
}

extern "C" void kernel_launch(void* const* d_in, const int* in_sizes, int n_in,
                              void* d_out, int out_size, void* d_ws, size_t ws_size,
                              hipStream_t stream) {
    const float* x    = (const float*)d_in[0];
    const int*   arr  = (const int*)d_in[1];
    const float* w    = (const float*)d_in[2];
    const float* bias = (const float*)d_in[3];
    float* out = (float*)d_out;

    // workspace: xp bf16 [8192][4096] (64MB) | wb bf16 [8][512][512] (4MB)
    unsigned short* xp = (unsigned short*)d_ws;
    unsigned short* wb = xp + (size_t)B_ROWS * C_IN;

    hipLaunchKernelGGL(convert_w_kernel, dim3((G_GRP * J_RANK * CG / 4 + 255) / 256),
                       dim3(256), 0, stream, w, wb, G_GRP * J_RANK * CG / 4);
    hipLaunchKernelGGL(permute_x_kernel, dim3(PERM_BLOCKS), dim3(256), 0, stream,
                       x, arr, xp);
    hipLaunchKernelGGL(gemm_kernel, dim3(G_GRP * 64), dim3(512), 0, stream,
                       xp, wb, bias, out);
}